// Round 12
// baseline (837.094 us; speedup 1.0000x reference)
//
#include <hip/hip_runtime.h>
#include <hip/hip_bf16.h>
#include <hip/hip_fp16.h>

typedef __attribute__((ext_vector_type(8))) short short8;
typedef __attribute__((ext_vector_type(4))) float f32x4;

#define TWARM 96
#define SOUT  24
#define WIN   24   // x staging window (timesteps per per-wave LDS window)
#define NWIN  (TWARM / WIN)
#define K1 1.44269504089f   // log2(e)
#define K2 2.88539008178f   // 2*log2(e)

// Intra-wave LDS write->read ordering fence (rule #18: sched_barrier after waitcnt)
#define LGKM_FENCE() do { \
    asm volatile("s_waitcnt lgkmcnt(0)" ::: "memory"); \
    __builtin_amdgcn_sched_barrier(0); \
} while (0)

static __device__ __forceinline__ short f2bf(float f) {
    __hip_bfloat16 h = __float2bfloat16(f);
    return *reinterpret_cast<short*>(&h);
}
static __device__ __forceinline__ float bf2f(short s) {
    unsigned u = ((unsigned)(unsigned short)s) << 16;
    return __builtin_bit_cast(float, u);
}

// Occupancy is register-capped at 2 waves/SIMD (r7-r11: arch+acc ~256/wave).
// So: ILP instead of TLP — each wave runs TWO independent 16-row LSTM chains
// (32 rows/wave, 128 rows/block, grid 512 = exactly 2 blocks/CU, no tail).
// Chain B's MFMA issue overlaps chain A's gate transcendentals inside one
// wave. Per chain per step: Z' = -K*(x@W + b + H@U) via 32 MFMAs in four
// gate-group quarters (A/B quarters interleaved); one LGKM fence per step.
__global__ void __launch_bounds__(256, 2)
lstm_ar_kernel(const float* __restrict__ gin, const float* __restrict__ gW,
               const float* __restrict__ gU, const float* __restrict__ gb,
               const float* __restrict__ gWd, const float* __restrict__ gbd,
               float* __restrict__ gout, int B)
{
    __shared__ __align__(16) short    U_lds[16384];        // 32 KB, swizzled B-frags
    __shared__ __align__(16) short    h_lds[4][32][72];    // 18 KB, per-wave padded
    __shared__ __align__(16) unsigned x_lds[4][32][WIN];   // 12 KB fp16-pair x; reused for preds
    __shared__ float wdc_lds[4][2][16];                    // 512 B

    const int tid  = threadIdx.x;
    const int wv   = tid >> 6;
    const int lane = tid & 63;
    const int c4   = lane & 15;   // MFMA col / A-row selector
    const int hi   = lane >> 4;   // MFMA k-group / C-row group

    // ---- stage U (coalesced read, swizzled LDS write, gate-scale folded) ----
    for (int idx = tid; idx < 16384; idx += 256) {
        int k = idx >> 8, col = idx & 255;
        float sc = ((col >> 6) == 2) ? -K2 : -K1;   // g columns get -2*log2e
        int dst = (((col >> 4) * 2 + (k >> 5)) * 4 + ((k & 31) >> 3)) * 128
                + (col & 15) * 8 + (k & 7);
        U_lds[dst] = f2bf(sc * gU[idx]);
    }
    // ---- Wd table ----
    if (tid < 128) {
        int tt = tid >> 5, j = (tid >> 4) & 1, cc = tid & 15;
        wdc_lds[tt][j][cc] = gWd[(tt * 16 + cc) * 2 + j];
    }

    // ---- per-lane constants: W rows + b, f32 (shared by both chains) ----
    float W0c[16], W1c[16], bc[16];
#pragma unroll
    for (int n = 0; n < 16; ++n) {
        int col = n * 16 + c4;
        float sc = (n >= 8 && n < 12) ? -K2 : -K1;
        W0c[n] = sc * gW[col];
        W1c[n] = sc * gW[256 + col];
        bc[n]  = sc * gb[col];
    }
    const float bd0 = gbd[0], bd1 = gbd[1];

    const int row0   = blockIdx.x * 128 + wv * 32;   // this wave's 32 rows
    const bool active = (row0 + 31) < B;

    // zero this wave's h buffer
    for (int i = lane; i < 32 * 72; i += 64) (&h_lds[wv][0][0])[i] = 0;

    // ---- per-wave x window staging: 32 rows x WIN steps, fp16 pairs ----
    const int xrow = lane >> 1, xq = lane & 1;   // 2 lanes/row, 24 floats each
    auto stage_x = [&](int w) {
        const float* src = gin + (size_t)(row0 + xrow) * (TWARM * 2)
                         + w * (WIN * 2) + xq * 24;
#pragma unroll
        for (int m = 0; m < 6; ++m) {
            float4 v = *reinterpret_cast<const float4*>(src + m * 4);
            uint2 pk;
            pk.x = __builtin_bit_cast(unsigned, __floats2half2_rn(v.x, v.y));
            pk.y = __builtin_bit_cast(unsigned, __floats2half2_rn(v.z, v.w));
            *reinterpret_cast<uint2*>(&x_lds[wv][xrow][xq * 12 + m * 2]) = pk;
        }
        LGKM_FENCE();   // window visible to this wave before first read
    };

    if (active) stage_x(0);
    __syncthreads();    // the ONLY block barrier: U + wdc staged & visible
    if (!active) return;

    float c_[2][4][4];  // pre-scaled: c' = -K2 * c ; [chain][tt][r]
#pragma unroll
    for (int ch = 0; ch < 2; ++ch)
#pragma unroll
        for (int tt = 0; tt < 4; ++tt)
#pragma unroll
            for (int r = 0; r < 4; ++r) c_[ch][tt][r] = 0.f;

    const short* hbase = &h_lds[wv][0][0];
    const short* hptr  = hbase + c4 * 72 + hi * 8;            // chain A A-frag base
    short*       hwptr = &h_lds[wv][0][0] + (hi * 4) * 72 + c4;  // chain A h write base
    const short* uptr  = U_lds + lane * 8;                    // B-frag read base
    // chain B: +16 rows = +1152 shorts (2304 B) on both bases

    float h_[2][4][4];  // live during decode only

    // ---- one LSTM step for BOTH chains; acc is z' = -K*z ----
    auto lstm_step = [&](const float xA0[4], const float xA1[4],
                         const float xB0[4], const float xB1[4], bool save_h) {
        short8 aA0 = *reinterpret_cast<const short8*>(hptr);
        short8 aA1 = *reinterpret_cast<const short8*>(hptr + 32);
        short8 aB0 = *reinterpret_cast<const short8*>(hptr + 1152);
        short8 aB1 = *reinterpret_cast<const short8*>(hptr + 1184);
#pragma unroll
        for (int tt = 0; tt < 4; ++tt) {
            f32x4 accA[4], accB[4];   // tiles n = tt+4j -> i,f,g,o
#pragma unroll
            for (int j = 0; j < 4; ++j) {
                const int n = tt + 4 * j;
#pragma unroll
                for (int r = 0; r < 4; ++r) {
                    accA[j][r] = fmaf(xA1[r], W1c[n], fmaf(xA0[r], W0c[n], bc[n]));
                    accB[j][r] = fmaf(xB1[r], W1c[n], fmaf(xB0[r], W0c[n], bc[n]));
                }
            }
#pragma unroll
            for (int j = 0; j < 4; ++j) {
                const int n = tt + 4 * j;
                short8 u0 = *reinterpret_cast<const short8*>(uptr + (n * 2 + 0) * 512);
                short8 u1 = *reinterpret_cast<const short8*>(uptr + (n * 2 + 1) * 512);
                accA[j] = __builtin_amdgcn_mfma_f32_16x16x32_bf16(aA0, u0, accA[j], 0, 0, 0);
                accA[j] = __builtin_amdgcn_mfma_f32_16x16x32_bf16(aA1, u1, accA[j], 0, 0, 0);
                accB[j] = __builtin_amdgcn_mfma_f32_16x16x32_bf16(aB0, u0, accB[j], 0, 0, 0);
                accB[j] = __builtin_amdgcn_mfma_f32_16x16x32_bf16(aB1, u1, accB[j], 0, 0, 0);
            }
            // gates per chain: ea=e^{-zi}, ef=e^{-zf}, eg=e^{-2zg}, eo=e^{-zo}
            // c' = sf*c' + (K2*eg - K2)*rcp((1+ea)(1+eg)); ec = exp2(c')
#pragma unroll
            for (int ch = 0; ch < 2; ++ch) {
#pragma unroll
                for (int r = 0; r < 4; ++r) {
                    const f32x4* ac = ch ? accB : accA;
                    float ea = __builtin_amdgcn_exp2f(ac[0][r]);
                    float ef = __builtin_amdgcn_exp2f(ac[1][r]);
                    float eg = __builtin_amdgcn_exp2f(ac[2][r]);
                    float eo = __builtin_amdgcn_exp2f(ac[3][r]);
                    float sf = __builtin_amdgcn_rcpf(1.0f + ef);
                    float sg = fmaf(eg, K2, -K2) *
                        __builtin_amdgcn_rcpf((1.0f + ea) * (1.0f + eg));
                    float cn = fmaf(sf, c_[ch][tt][r], sg);
                    c_[ch][tt][r] = cn;
                    float ec = __builtin_amdgcn_exp2f(cn);
                    float hn = (1.0f - ec) *
                        __builtin_amdgcn_rcpf((1.0f + eo) * (1.0f + ec));
                    if (save_h) h_[ch][tt][r] = hn;
                    hwptr[ch * 1152 + r * 72 + tt * 16] = f2bf(hn);
                }
            }
        }
        LGKM_FENCE();   // all h writes land before next step's A-frag reads
    };

    // ---- warmup: 96 steps, x from this wave's LDS windows ----
#pragma unroll 1
    for (int w = 0; w < NWIN; ++w) {
        if (w != 0) stage_x(w);   // prior step's fence ordered old-window reads
#pragma unroll 1
        for (int tl = 0; tl < WIN; ++tl) {
            float xA0[4], xA1[4], xB0[4], xB1[4];
#pragma unroll
            for (int r = 0; r < 4; ++r) {
                __half2 ha = __builtin_bit_cast(__half2, x_lds[wv][hi * 4 + r][tl]);
                __half2 hb = __builtin_bit_cast(__half2, x_lds[wv][16 + hi * 4 + r][tl]);
                xA0[r] = __low2float(ha); xA1[r] = __high2float(ha);
                xB0[r] = __low2float(hb); xB1[r] = __high2float(hb);
            }
            lstm_step(xA0, xA1, xB0, xB1, false);
        }
    }

    // rebuild h_ (f32) from the bf16 LDS copy once after warmup
#pragma unroll
    for (int ch = 0; ch < 2; ++ch)
#pragma unroll
        for (int tt = 0; tt < 4; ++tt)
#pragma unroll
            for (int r = 0; r < 4; ++r)
                h_[ch][tt][r] =
                    bf2f(hbase[(ch * 16 + hi * 4 + r) * 72 + tt * 16 + c4]);

    // hoist Wd for this lane's cols (decode-only registers)
    float wdc[4][2];
#pragma unroll
    for (int tt = 0; tt < 4; ++tt) {
        wdc[tt][0] = wdc_lds[tt][0][c4];
        wdc[tt][1] = wdc_lds[tt][1][c4];
    }

    // ---- decode: pred = h@Wd + bd per chain, butterfly over 16-lane groups ----
    auto make_pred = [&](int ch, float* p0, float* p1) {
#pragma unroll
        for (int r = 0; r < 4; ++r) {
            float a0 = 0.f, a1 = 0.f;
#pragma unroll
            for (int tt = 0; tt < 4; ++tt) {
                a0 = fmaf(h_[ch][tt][r], wdc[tt][0], a0);
                a1 = fmaf(h_[ch][tt][r], wdc[tt][1], a1);
            }
            p0[r] = a0; p1[r] = a1;
        }
#pragma unroll
        for (int m = 1; m < 16; m <<= 1)
#pragma unroll
            for (int r = 0; r < 4; ++r) {
                p0[r] += __shfl_xor(p0[r], m, 64);
                p1[r] += __shfl_xor(p1[r], m, 64);
            }
#pragma unroll
        for (int r = 0; r < 4; ++r) { p0[r] += bd0; p1[r] += bd1; }
    };
    // stash pred fp16 in this wave's (dead) x window; feedback stays f32 regs
    auto store_pred = [&](int ch, int s, const float* p0, const float* p1) {
        if (c4 == 0) {
#pragma unroll
            for (int r = 0; r < 4; ++r)
                x_lds[wv][ch * 16 + hi * 4 + r][s] =
                    __builtin_bit_cast(unsigned, __floats2half2_rn(p0[r], p1[r]));
        }
    };

    float pA0[4], pA1[4], pB0[4], pB1[4];
    make_pred(0, pA0, pA1);
    make_pred(1, pB0, pB1);
    store_pred(0, 0, pA0, pA1);
    store_pred(1, 0, pB0, pB1);
#pragma unroll 1
    for (int s = 1; s < SOUT; ++s) {
        lstm_step(pA0, pA1, pB0, pB1, true);
        make_pred(0, pA0, pA1);
        make_pred(1, pB0, pB1);
        store_pred(0, s, pA0, pA1);
        store_pred(1, s, pB0, pB1);
    }
    LGKM_FENCE();   // all pred stashes of this wave visible to this wave

    // ---- per-wave coalesced writeout: 32 rows x 48 floats ----
#pragma unroll
    for (int k = 0; k < 12; ++k) {
        unsigned u = x_lds[wv][xrow][xq * 12 + k];
        __half2 hv = __builtin_bit_cast(__half2, u);
        *reinterpret_cast<float2*>(
            gout + (size_t)(row0 + xrow) * (SOUT * 2) + (xq * 12 + k) * 2) =
            make_float2(__low2float(hv), __high2float(hv));
    }
}

extern "C" void kernel_launch(void* const* d_in, const int* in_sizes, int n_in,
                              void* d_out, int out_size, void* d_ws, size_t ws_size,
                              hipStream_t stream) {
    const float* gin  = (const float*)d_in[0];
    const float* gW   = (const float*)d_in[1];
    const float* gU   = (const float*)d_in[2];
    const float* gb   = (const float*)d_in[3];
    const float* gWd  = (const float*)d_in[4];
    const float* gbd  = (const float*)d_in[5];
    float* gout = (float*)d_out;

    const int B = in_sizes[0] / (TWARM * 2);
    const int blocks = (B + 127) / 128;
    lstm_ar_kernel<<<blocks, 256, 0, stream>>>(gin, gW, gU, gb, gWd, gbd, gout, B);
}

// Round 13
// 804.082 us; speedup vs baseline: 1.0411x; 1.0411x over previous
//
#include <hip/hip_runtime.h>
#include <hip/hip_bf16.h>
#include <hip/hip_fp16.h>

typedef __attribute__((ext_vector_type(8))) short short8;
typedef __attribute__((ext_vector_type(4))) float f32x4;

#define TWARM 96
#define SOUT  24
#define WIN   24   // x staging window (timesteps per per-wave LDS window)
#define NWIN  (TWARM / WIN)
#define K1 1.44269504089f   // log2(e)
#define K2 2.88539008178f   // 2*log2(e)

// Intra-wave LDS write->read ordering fence (rule #18: sched_barrier after waitcnt)
#define LGKM_FENCE() do { \
    asm volatile("s_waitcnt lgkmcnt(0)" ::: "memory"); \
    __builtin_amdgcn_sched_barrier(0); \
} while (0)

static __device__ __forceinline__ short f2bf(float f) {
    __hip_bfloat16 h = __float2bfloat16(f);
    return *reinterpret_cast<short*>(&h);
}
static __device__ __forceinline__ float bf2f(short s) {
    unsigned u = ((unsigned)(unsigned short)s) << 16;
    return __builtin_bit_cast(float, u);
}

// One wave owns 16 batch rows for all 119 steps; waves fully independent after
// the single init barrier. Per step: Z' = -K*(x@W + b + H@U) via 32 MFMAs in
// four gate-group quarters (acc peak 16 regs). KEY this round: a
// sched_barrier(0) at each quarter boundary stops the scheduler from hoisting
// all 32 loop-invariant u-frag ds_reads (128 VGPRs of transients) across the
// step body — the identified source of the persistent 0.5 GB scratch-spill
// FETCH at the 128-VGPR allocation cap (r7-r12).
__global__ void __launch_bounds__(256, 2)
lstm_ar_kernel(const float* __restrict__ gin, const float* __restrict__ gW,
               const float* __restrict__ gU, const float* __restrict__ gb,
               const float* __restrict__ gWd, const float* __restrict__ gbd,
               float* __restrict__ gout, int B)
{
    __shared__ __align__(16) short    U_lds[16384];        // 32 KB, swizzled B-frags
    __shared__ __align__(16) short    h_lds[4][16][72];    // 9 KB, per-wave padded
    __shared__ __align__(16) unsigned x_lds[4][16][WIN];   // 6 KB fp16-pair x; reused for preds
    __shared__ float wdc_lds[4][2][16];                    // 512 B

    const int tid  = threadIdx.x;
    const int wv   = tid >> 6;
    const int lane = tid & 63;
    const int c4   = lane & 15;   // MFMA col / A-row selector
    const int hi   = lane >> 4;   // MFMA k-group / C-row group

    // ---- stage U (coalesced read, swizzled LDS write, gate-scale folded) ----
    for (int idx = tid; idx < 16384; idx += 256) {
        int k = idx >> 8, col = idx & 255;
        float sc = ((col >> 6) == 2) ? -K2 : -K1;   // g columns get -2*log2e
        int dst = (((col >> 4) * 2 + (k >> 5)) * 4 + ((k & 31) >> 3)) * 128
                + (col & 15) * 8 + (k & 7);
        U_lds[dst] = f2bf(sc * gU[idx]);
    }
    // ---- Wd table ----
    if (tid < 128) {
        int tt = tid >> 5, j = (tid >> 4) & 1, cc = tid & 15;
        wdc_lds[tt][j][cc] = gWd[(tt * 16 + cc) * 2 + j];
    }

    // ---- per-lane constants: W and b packed fp16 (scale folded) ----
    unsigned Wp[16], Bp[8];
#pragma unroll
    for (int n = 0; n < 16; ++n) {
        int col = n * 16 + c4;
        float sc = (n >= 8 && n < 12) ? -K2 : -K1;
        __half2 wp = __floats2half2_rn(sc * gW[col], sc * gW[256 + col]);
        Wp[n] = __builtin_bit_cast(unsigned, wp);
    }
#pragma unroll
    for (int m = 0; m < 8; ++m) {
        int n0 = 2 * m, n1 = 2 * m + 1;
        float s0 = (n0 >= 8 && n0 < 12) ? -K2 : -K1;
        float s1 = (n1 >= 8 && n1 < 12) ? -K2 : -K1;
        __half2 bp = __floats2half2_rn(s0 * gb[n0 * 16 + c4], s1 * gb[n1 * 16 + c4]);
        Bp[m] = __builtin_bit_cast(unsigned, bp);
    }
    const float bd0 = gbd[0], bd1 = gbd[1];

    const int row0   = blockIdx.x * 64 + wv * 16;
    const bool active = (row0 + 15) < B;

    // zero this wave's h buffer
    for (int i = lane; i < 16 * 72; i += 64) (&h_lds[wv][0][0])[i] = 0;

    // ---- per-wave x window staging: 16 rows x WIN steps, fp16 pairs ----
    const int xrow = lane >> 2, xq = lane & 3;   // 4 lanes/row, 12 floats each
    auto stage_x = [&](int w) {
        const float* src = gin + (size_t)(row0 + xrow) * (TWARM * 2)
                         + w * (WIN * 2) + xq * 12;
#pragma unroll
        for (int m = 0; m < 3; ++m) {
            float4 v = *reinterpret_cast<const float4*>(src + m * 4);
            uint2 pk;
            pk.x = __builtin_bit_cast(unsigned, __floats2half2_rn(v.x, v.y));
            pk.y = __builtin_bit_cast(unsigned, __floats2half2_rn(v.z, v.w));
            *reinterpret_cast<uint2*>(&x_lds[wv][xrow][xq * 6 + m * 2]) = pk;
        }
        LGKM_FENCE();   // window visible to this wave before first read
    };

    if (active) stage_x(0);
    __syncthreads();    // the ONLY block barrier: U + wdc staged & visible
    if (!active) return;

    float c_[4][4];     // pre-scaled: c' = -K2 * c
#pragma unroll
    for (int tt = 0; tt < 4; ++tt)
#pragma unroll
        for (int r = 0; r < 4; ++r) c_[tt][r] = 0.f;

    const short* hptr  = &h_lds[wv][0][0] + c4 * 72 + hi * 8;     // A-frag read base
    short*       hwptr = &h_lds[wv][0][0] + (hi * 4) * 72 + c4;   // h write base
    const short* uptr  = U_lds + lane * 8;                        // B-frag read base

    float h_[4][4];     // live during decode only

    // ---- one LSTM step; acc is z' = -K*z; four gate-group quarters,
    //      sched_barrier(0) at each quarter boundary caps u-frag hoisting ----
    auto lstm_step = [&](const float x0[4], const float x1[4], bool save_h) {
        short8 a0v = *reinterpret_cast<const short8*>(hptr);
        short8 a1v = *reinterpret_cast<const short8*>(hptr + 32);
#pragma unroll
        for (int tt = 0; tt < 4; ++tt) {
            f32x4 acc[4];   // tiles n = tt, tt+4, tt+8, tt+12 -> i,f,g,o
#pragma unroll
            for (int j = 0; j < 4; ++j) {
                const int n = tt + 4 * j;
                __half2 wp = __builtin_bit_cast(__half2, Wp[n]);
                float w0 = __low2float(wp), w1 = __high2float(wp);
                __half2 bp = __builtin_bit_cast(__half2, Bp[n >> 1]);
                float bv = (n & 1) ? __high2float(bp) : __low2float(bp);
#pragma unroll
                for (int r = 0; r < 4; ++r)
                    acc[j][r] = fmaf(x1[r], w1, fmaf(x0[r], w0, bv));
            }
#pragma unroll
            for (int j = 0; j < 4; ++j) {
                const int n = tt + 4 * j;
                short8 u0 = *reinterpret_cast<const short8*>(uptr + (n * 2 + 0) * 512);
                short8 u1 = *reinterpret_cast<const short8*>(uptr + (n * 2 + 1) * 512);
                acc[j] = __builtin_amdgcn_mfma_f32_16x16x32_bf16(a0v, u0, acc[j], 0, 0, 0);
                acc[j] = __builtin_amdgcn_mfma_f32_16x16x32_bf16(a1v, u1, acc[j], 0, 0, 0);
            }
            // ea=e^{-zi}, ef=e^{-zf}, eg=e^{-2zg}, eo=e^{-zo}
            // c' update: c'n = sf*c' + (K2*eg - K2)*rcp((1+ea)(1+eg)); ec = exp2(c'n)
#pragma unroll
            for (int r = 0; r < 4; ++r) {
                float ea = __builtin_amdgcn_exp2f(acc[0][r]);
                float ef = __builtin_amdgcn_exp2f(acc[1][r]);
                float eg = __builtin_amdgcn_exp2f(acc[2][r]);
                float eo = __builtin_amdgcn_exp2f(acc[3][r]);
                float sf = __builtin_amdgcn_rcpf(1.0f + ef);
                float sg = fmaf(eg, K2, -K2) *
                    __builtin_amdgcn_rcpf((1.0f + ea) * (1.0f + eg));
                float cn = fmaf(sf, c_[tt][r], sg);
                c_[tt][r] = cn;
                float ec = __builtin_amdgcn_exp2f(cn);
                float hn = (1.0f - ec) *
                    __builtin_amdgcn_rcpf((1.0f + eo) * (1.0f + ec));
                if (save_h) h_[tt][r] = hn;
                hwptr[r * 72 + tt * 16] = f2bf(hn);
            }
            // Quarter boundary: nothing (esp. next quarter's ds_reads) moves
            // above this point -> max 8 u-frags in flight, live set < 128.
            __builtin_amdgcn_sched_barrier(0);
        }
        LGKM_FENCE();   // h writes land before next step's A-frag reads
    };

    // ---- warmup: 96 steps, x from this wave's LDS windows ----
#pragma unroll 1
    for (int w = 0; w < NWIN; ++w) {
        if (w != 0) stage_x(w);   // prior step's fence ordered old-window reads
#pragma unroll 1
        for (int tl = 0; tl < WIN; ++tl) {
            float x0[4], x1[4];
#pragma unroll
            for (int r = 0; r < 4; ++r) {
                __half2 hx = __builtin_bit_cast(__half2, x_lds[wv][hi * 4 + r][tl]);
                x0[r] = __low2float(hx);
                x1[r] = __high2float(hx);
            }
            lstm_step(x0, x1, false);
        }
    }

    // rebuild h_ (f32) from the bf16 LDS copy once after warmup
#pragma unroll
    for (int tt = 0; tt < 4; ++tt)
#pragma unroll
        for (int r = 0; r < 4; ++r)
            h_[tt][r] = bf2f((&h_lds[wv][0][0])[(hi * 4 + r) * 72 + tt * 16 + c4]);

    // hoist Wd for this lane's cols (decode-only registers)
    float wdc[4][2];
#pragma unroll
    for (int tt = 0; tt < 4; ++tt) {
        wdc[tt][0] = wdc_lds[tt][0][c4];
        wdc[tt][1] = wdc_lds[tt][1][c4];
    }

    // ---- decode: pred = h@Wd + bd, butterfly over the 16-lane col group ----
    auto make_pred = [&](float* p0, float* p1) {
#pragma unroll
        for (int r = 0; r < 4; ++r) {
            float a0 = 0.f, a1 = 0.f;
#pragma unroll
            for (int tt = 0; tt < 4; ++tt) {
                a0 = fmaf(h_[tt][r], wdc[tt][0], a0);
                a1 = fmaf(h_[tt][r], wdc[tt][1], a1);
            }
            p0[r] = a0; p1[r] = a1;
        }
#pragma unroll
        for (int m = 1; m < 16; m <<= 1)
#pragma unroll
            for (int r = 0; r < 4; ++r) {
                p0[r] += __shfl_xor(p0[r], m, 64);
                p1[r] += __shfl_xor(p1[r], m, 64);
            }
#pragma unroll
        for (int r = 0; r < 4; ++r) { p0[r] += bd0; p1[r] += bd1; }
    };
    // stash pred fp16 in this wave's (dead) x window; feedback stays f32 regs
    auto store_pred = [&](int s, const float* p0, const float* p1) {
        if (c4 == 0) {
#pragma unroll
            for (int r = 0; r < 4; ++r)
                x_lds[wv][hi * 4 + r][s] =
                    __builtin_bit_cast(unsigned, __floats2half2_rn(p0[r], p1[r]));
        }
    };

    float p0[4], p1[4];
    make_pred(p0, p1);
    store_pred(0, p0, p1);
#pragma unroll 1
    for (int s = 1; s < SOUT; ++s) {
        lstm_step(p0, p1, true);
        make_pred(p0, p1);
        store_pred(s, p0, p1);
    }
    LGKM_FENCE();   // all pred stashes of this wave visible to this wave

    // ---- per-wave coalesced writeout: 16 rows x 48 floats ----
#pragma unroll
    for (int m = 0; m < 6; ++m) {
        unsigned u = x_lds[wv][xrow][xq * 6 + m];
        __half2 hv = __builtin_bit_cast(__half2, u);
        *reinterpret_cast<float2*>(
            gout + (size_t)(row0 + xrow) * (SOUT * 2) + xq * 12 + m * 2) =
            make_float2(__low2float(hv), __high2float(hv));
    }
}

extern "C" void kernel_launch(void* const* d_in, const int* in_sizes, int n_in,
                              void* d_out, int out_size, void* d_ws, size_t ws_size,
                              hipStream_t stream) {
    const float* gin  = (const float*)d_in[0];
    const float* gW   = (const float*)d_in[1];
    const float* gU   = (const float*)d_in[2];
    const float* gb   = (const float*)d_in[3];
    const float* gWd  = (const float*)d_in[4];
    const float* gbd  = (const float*)d_in[5];
    float* gout = (float*)d_out;

    const int B = in_sizes[0] / (TWARM * 2);
    const int blocks = (B + 63) / 64;
    lstm_ar_kernel<<<blocks, 256, 0, stream>>>(gin, gW, gU, gb, gWd, gbd, gout, B);
}